// Round 3
// baseline (65.756 us; speedup 1.0000x reference)
//
#include <hip/hip_runtime.h>

#define BB 2
#define NN 512
#define DD 64
#define LN_EPS 1e-5f
#define NEG_SLOPE 0.01f

typedef float f32x4 __attribute__((ext_vector_type(4)));

__device__ __forceinline__ float wave_reduce_sum(float v) {
    #pragma unroll
    for (int off = 32; off >= 1; off >>= 1)
        v += __shfl_xor(v, off, 64);
    return v;
}

__device__ __forceinline__ float wave_reduce_max(float v) {
    #pragma unroll
    for (int off = 32; off >= 1; off >>= 1)
        v = fmaxf(v, __shfl_xor(v, off, 64));
    return v;
}

// One 64-lane wave per row. Rows 0..B*N-1: ua rows -> sq, sk.
// Rows B*N..B*N+B-1: iid rows -> c[b] = siid + b_att.
__global__ __launch_bounds__(64) void precompute_kernel(
    const float* __restrict__ ua,
    const float* __restrict__ iid,
    const float* __restrict__ ln_g,
    const float* __restrict__ ln_b,
    const float* __restrict__ w_att,
    const float* __restrict__ b_att,
    float* __restrict__ sq,
    float* __restrict__ sk,
    float* __restrict__ cb) {
    const int bid = blockIdx.x;
    const int lane = threadIdx.x;

    const float g = ln_g[lane];
    const float bet = ln_b[lane];

    if (bid < BB * NN) {
        float x = ua[bid * DD + lane];
        float m = wave_reduce_sum(x) * (1.0f / DD);
        float xc = x - m;
        float var = wave_reduce_sum(xc * xc) * (1.0f / DD);
        float r = rsqrtf(var + LN_EPS);
        float w = xc * r * g + bet;
        float s1 = wave_reduce_sum(w * w_att[lane]);
        float s2 = wave_reduce_sum(w * w_att[DD + lane]);
        if (lane == 0) {
            sq[bid] = s1;
            sk[bid] = s2;
        }
    } else {
        int b = bid - BB * NN;
        float x = iid[b * DD + lane];
        float m = wave_reduce_sum(x) * (1.0f / DD);
        float xc = x - m;
        float var = wave_reduce_sum(xc * xc) * (1.0f / DD);
        float r = rsqrtf(var + LN_EPS);
        float w = xc * r * g + bet;
        float s3 = wave_reduce_sum(w * w_att[2 * DD + lane]);
        if (lane == 0) {
            cb[b] = s3 + b_att[0];
        }
    }
}

// One block per (b, i, half) — 2048 blocks. Full softmax over j (512, cheap,
// recomputed per half), then stream this half's 2x64KB of outputs with
// nontemporal f32x4 stores.
__global__ __launch_bounds__(256) void write_kernel(
    const float* __restrict__ ua,
    const float* __restrict__ sq,
    const float* __restrict__ sk,
    const float* __restrict__ cb,
    float* __restrict__ out0,   // alphas broadcast [B,N,N,D]
    float* __restrict__ out1) { // value = q*k      [B,N,N,D]
    __shared__ float alpha_sh[256];
    __shared__ float red_mx[4];
    __shared__ float red_sm[4];

    const int bid2 = blockIdx.x;
    const int row  = bid2 >> 1;        // b*N + i
    const int half = bid2 & 1;         // which 256-j half this block writes
    const int b = row >> 9;            // / NN
    const int i = row & (NN - 1);
    const int tid = threadIdx.x;

    const float sqi = sq[row];
    const float c = cb[b];

    // full-row scores (this thread's two j's)
    float s0 = sqi + sk[b * NN + tid] + c;
    float s1 = sqi + sk[b * NN + tid + 256] + c;
    s0 = (s0 >= 0.0f) ? s0 : NEG_SLOPE * s0;
    s1 = (s1 >= 0.0f) ? s1 : NEG_SLOPE * s1;

    // block max over all 512
    float mx = fmaxf(s0, s1);
    mx = wave_reduce_max(mx);
    const int wid = tid >> 6;
    if ((tid & 63) == 0) red_mx[wid] = mx;
    __syncthreads();
    mx = fmaxf(fmaxf(red_mx[0], red_mx[1]), fmaxf(red_mx[2], red_mx[3]));

    // block sum of exp over all 512
    float e0 = expf(s0 - mx);
    float e1 = expf(s1 - mx);
    float sm = wave_reduce_sum(e0 + e1);
    if ((tid & 63) == 0) red_sm[wid] = sm;
    __syncthreads();
    sm = red_sm[0] + red_sm[1] + red_sm[2] + red_sm[3];
    const float inv = 1.0f / sm;

    // stash only this half's alphas (local j index 0..255)
    alpha_sh[tid] = (half ? e1 : e0) * inv;
    __syncthreads();

    // write phase: per-thread fixed d4 = tid&15, local j walks jbase + k*16
    const int d4 = tid & 15;
    const int jbase = tid >> 4;

    const f32x4* __restrict__ uaB = (const f32x4*)(ua + (size_t)b * NN * DD);
    const f32x4 ui = uaB[(size_t)i * 16 + d4];
    const f32x4* __restrict__ uaH = uaB + (size_t)half * 256 * 16;

    f32x4* __restrict__ o0 =
        (f32x4*)(out0 + (size_t)row * NN * DD + (size_t)half * 256 * DD);
    f32x4* __restrict__ o1 =
        (f32x4*)(out1 + (size_t)row * NN * DD + (size_t)half * 256 * DD);

    #pragma unroll 4
    for (int k = 0; k < 16; ++k) {
        const int jl = jbase + k * 16;      // local j in [0,256)
        const float a = alpha_sh[jl];
        const f32x4 uj = uaH[jl * 16 + d4];
        f32x4 av;
        av.x = a; av.y = a; av.z = a; av.w = a;
        f32x4 val = ui * uj;
        __builtin_nontemporal_store(av,  &o0[jl * 16 + d4]);
        __builtin_nontemporal_store(val, &o1[jl * 16 + d4]);
    }
}

extern "C" void kernel_launch(void* const* d_in, const int* in_sizes, int n_in,
                              void* d_out, int out_size, void* d_ws, size_t ws_size,
                              hipStream_t stream) {
    const float* ua    = (const float*)d_in[0];
    const float* iid   = (const float*)d_in[1];
    const float* ln_g  = (const float*)d_in[2];
    const float* ln_b  = (const float*)d_in[3];
    const float* w_att = (const float*)d_in[4];
    const float* b_att = (const float*)d_in[5];

    float* out0 = (float*)d_out;                                // alphas [B,N,N,D]
    float* out1 = out0 + (size_t)BB * NN * NN * DD;             // value  [B,N,N,D]

    float* sq = (float*)d_ws;          // B*N
    float* sk = sq + BB * NN;          // B*N
    float* cb = sk + BB * NN;          // B

    precompute_kernel<<<BB * NN + BB, 64, 0, stream>>>(ua, iid, ln_g, ln_b,
                                                       w_att, b_att, sq, sk, cb);
    write_kernel<<<BB * NN * 2, 256, 0, stream>>>(ua, sq, sk, cb, out0, out1);
}

// Round 4
// 50.484 us; speedup vs baseline: 1.3025x; 1.3025x over previous
//
#include <hip/hip_runtime.h>

#define BB 2
#define NN 512
#define DD 64
#define LN_EPS 1e-5f
#define NEG_SLOPE 0.01f

typedef float f32x4 __attribute__((ext_vector_type(4)));

__device__ __forceinline__ float wave_reduce_sum(float v) {
    #pragma unroll
    for (int off = 32; off >= 1; off >>= 1)
        v += __shfl_xor(v, off, 64);
    return v;
}

__device__ __forceinline__ float wave_reduce_max(float v) {
    #pragma unroll
    for (int off = 32; off >= 1; off >>= 1)
        v = fmaxf(v, __shfl_xor(v, off, 64));
    return v;
}

// One 64-lane wave per row. Rows 0..B*N-1: ua rows -> sq, sk.
// Rows B*N..B*N+B-1: iid rows -> c[b] = siid + b_att.
__global__ __launch_bounds__(64) void precompute_kernel(
    const float* __restrict__ ua,
    const float* __restrict__ iid,
    const float* __restrict__ ln_g,
    const float* __restrict__ ln_b,
    const float* __restrict__ w_att,
    const float* __restrict__ b_att,
    float* __restrict__ sq,
    float* __restrict__ sk,
    float* __restrict__ cb) {
    const int bid = blockIdx.x;
    const int lane = threadIdx.x;

    const float g = ln_g[lane];
    const float bet = ln_b[lane];

    if (bid < BB * NN) {
        float x = ua[bid * DD + lane];
        float m = wave_reduce_sum(x) * (1.0f / DD);
        float xc = x - m;
        float var = wave_reduce_sum(xc * xc) * (1.0f / DD);
        float r = rsqrtf(var + LN_EPS);
        float w = xc * r * g + bet;
        float s1 = wave_reduce_sum(w * w_att[lane]);
        float s2 = wave_reduce_sum(w * w_att[DD + lane]);
        if (lane == 0) {
            sq[bid] = s1;
            sk[bid] = s2;
        }
    } else {
        int b = bid - BB * NN;
        float x = iid[b * DD + lane];
        float m = wave_reduce_sum(x) * (1.0f / DD);
        float xc = x - m;
        float var = wave_reduce_sum(xc * xc) * (1.0f / DD);
        float r = rsqrtf(var + LN_EPS);
        float w = xc * r * g + bet;
        float s3 = wave_reduce_sum(w * w_att[2 * DD + lane]);
        if (lane == 0) {
            cb[b] = s3 + b_att[0];
        }
    }
}

// One block per (b, i, half) — 2048 blocks. Full softmax over j (512, cheap,
// recomputed per half). Then wave-specialized streaming:
//   waves 0-1: out0 (alpha broadcast, no load dependence)
//   waves 2-3: out1 (ui*uj, uj L2-resident)
__global__ __launch_bounds__(256) void write_kernel(
    const float* __restrict__ ua,
    const float* __restrict__ sq,
    const float* __restrict__ sk,
    const float* __restrict__ cb,
    float* __restrict__ out0,   // alphas broadcast [B,N,N,D]
    float* __restrict__ out1) { // value = q*k      [B,N,N,D]
    __shared__ float alpha_sh[256];
    __shared__ float red_mx[4];
    __shared__ float red_sm[4];

    const int bid2 = blockIdx.x;
    const int row  = bid2 >> 1;        // b*N + i
    const int half = bid2 & 1;         // which 256-j half this block writes
    const int b = row >> 9;            // / NN
    const int i = row & (NN - 1);
    const int tid = threadIdx.x;

    const float sqi = sq[row];
    const float c = cb[b];

    // full-row scores (this thread's two j's); leaky_relu = fmax(s, 0.01s)
    float s0 = sqi + sk[b * NN + tid] + c;
    float s1 = sqi + sk[b * NN + tid + 256] + c;
    s0 = fmaxf(s0, NEG_SLOPE * s0);
    s1 = fmaxf(s1, NEG_SLOPE * s1);

    // block max over all 512
    float mx = fmaxf(s0, s1);
    mx = wave_reduce_max(mx);
    const int wid = tid >> 6;
    if ((tid & 63) == 0) red_mx[wid] = mx;
    __syncthreads();
    mx = fmaxf(fmaxf(red_mx[0], red_mx[1]), fmaxf(red_mx[2], red_mx[3]));

    // block sum of exp over all 512
    float e0 = __expf(s0 - mx);
    float e1 = __expf(s1 - mx);
    float sm = wave_reduce_sum(e0 + e1);
    if ((tid & 63) == 0) red_sm[wid] = sm;
    __syncthreads();
    sm = red_sm[0] + red_sm[1] + red_sm[2] + red_sm[3];
    const float inv = 1.0f / sm;

    // stash this half's alphas (local j index 0..255)
    alpha_sh[tid] = (half ? e1 : e0) * inv;
    __syncthreads();

    // write phase. Region = 4096 f32x4 (256 j x 16 d4), contiguous.
    // Two waves cover it: lane l writes idx = l + k*128, k = 0..31
    // (2 KB contiguous per iteration across the wave-pair).
    const f32x4* __restrict__ uaB = (const f32x4*)(ua + (size_t)b * NN * DD);
    const f32x4* __restrict__ uaH = uaB + (size_t)half * 256 * 16;

    f32x4* __restrict__ o0 =
        (f32x4*)(out0 + (size_t)row * NN * DD + (size_t)half * 256 * DD);
    f32x4* __restrict__ o1 =
        (f32x4*)(out1 + (size_t)row * NN * DD + (size_t)half * 256 * DD);

    if (tid < 128) {
        // out0: pure alpha-broadcast store stream
        const int l = tid;
        #pragma unroll 4
        for (int k = 0; k < 32; ++k) {
            const int idx = l + k * 128;
            const float a = alpha_sh[idx >> 4];
            f32x4 av;
            av.x = a; av.y = a; av.z = a; av.w = a;
            o0[idx] = av;
        }
    } else {
        // out1: ui * uj
        const int l = tid - 128;
        const f32x4 ui = uaB[(size_t)i * 16 + (l & 15)];
        #pragma unroll 4
        for (int k = 0; k < 32; ++k) {
            const int idx = l + k * 128;
            const f32x4 uj = uaH[idx];
            o1[idx] = ui * uj;
        }
    }
}

extern "C" void kernel_launch(void* const* d_in, const int* in_sizes, int n_in,
                              void* d_out, int out_size, void* d_ws, size_t ws_size,
                              hipStream_t stream) {
    const float* ua    = (const float*)d_in[0];
    const float* iid   = (const float*)d_in[1];
    const float* ln_g  = (const float*)d_in[2];
    const float* ln_b  = (const float*)d_in[3];
    const float* w_att = (const float*)d_in[4];
    const float* b_att = (const float*)d_in[5];

    float* out0 = (float*)d_out;                                // alphas [B,N,N,D]
    float* out1 = out0 + (size_t)BB * NN * NN * DD;             // value  [B,N,N,D]

    float* sq = (float*)d_ws;          // B*N
    float* sk = sq + BB * NN;          // B*N
    float* cb = sk + BB * NN;          // B

    precompute_kernel<<<BB * NN + BB, 64, 0, stream>>>(ua, iid, ln_g, ln_b,
                                                       w_att, b_att, sq, sk, cb);
    write_kernel<<<BB * NN * 2, 256, 0, stream>>>(ua, sq, sk, cb, out0, out1);
}